// Round 12
// baseline (284.618 us; speedup 1.0000x reference)
//
#include <hip/hip_runtime.h>
#include <math.h>

// LSTM B=8192,T=512,IN=3,H=32,OUT=2 fp32.
// R20 = R19 chassis with two cuts:
// 1) Single-pass MFMA (W-lo dropped too): acc = Ah*Bh + xp. 2 MFMA/wave-step
//    (was 4), chain depth 1. Error budget: h-lo drop added ~1e-3 (measured
//    R13->R19: 9.8e-4 -> 1.95e-3); W-lo drop adds a similar term ->
//    predicted absmax ~4e-3 vs threshold 6.8e-3.
// 2) Post-barrier shadow: xp(t+1) compute + x(t+2) prefetch moved AFTER the
//    barrier + B ds_read, so their ~30 cyc of VALU covers the ds_read's
//    ~120-cyc latency into the loop-top MFMA (they previously sat between
//    MFMA and gates, where the chain is only ~50 cyc).
// Both shorten the per-wave serial span (~550 -> ~450 cyc) so the two
// anti-phased waves/SIMD can tile the step period: R19 idle was ~290
// cyc/step with VALU 607 + MFMA 137.
// Unchanged from R19/R13: 4-wave blocks, 16 batches, adjacent-unit A-perm
// R(m)=32*(m&3)+8w+2*(m>>2)+c (lane units u0=8w+2q,u0+1; acc_c[r]=gate r,
// zero selects), pk-f32x2 gates w/ fused triple-rcp, exact fp32 xp in MFMA
// C, cvt_pk h-pack, single hi-plane double-buffered LDS [2][16][40],
// lgkm-only barrier (1/step), block-parity s_sleep stagger, grid 512x256.

namespace {
constexpr int   kT      = 512;
constexpr float kL2E    = 1.44269504088896340736f;
constexpr int   kStride = 40;   // ushorts per LDS row: 32 units + 8 pad
}

typedef __bf16 bf16x8 __attribute__((ext_vector_type(8)));
typedef float  f32x4  __attribute__((ext_vector_type(4)));
typedef float  f32x2  __attribute__((ext_vector_type(2)));
typedef unsigned int u32x4 __attribute__((ext_vector_type(4)));

union Frag {
    bf16x8 v;
    unsigned short u[8];
    unsigned int   d[4];
    u32x4          q4;
};

__device__ __forceinline__ unsigned short bf_rne(float f) {
    unsigned u = __float_as_uint(f);
    u += 0x7fffu + ((u >> 16) & 1u);
    return (unsigned short)(u >> 16);
}
__device__ __forceinline__ float bf_tof(unsigned short h) {
    return __uint_as_float((unsigned)h << 16);
}
__device__ __forceinline__ float fast_exp2(float v) { return __builtin_amdgcn_exp2f(v); }
__device__ __forceinline__ float fast_rcp(float v)  { return __builtin_amdgcn_rcpf(v); }

// v_cvt_pk_bf16_f32: dst = [lo16 = bf16_rne(a), hi16 = bf16_rne(b)]
__device__ __forceinline__ unsigned cvt_pk_bf16(float a, float b) {
    unsigned r;
    asm("v_cvt_pk_bf16_f32 %0, %1, %2" : "=v"(r) : "v"(a), "v"(b));
    return r;
}

__device__ __forceinline__ f32x2 fma2(f32x2 a, f32x2 b, f32x2 c) {
    return __builtin_elementwise_fma(a, b, c);
}
__device__ __forceinline__ f32x2 exp22(f32x2 v) {
    f32x2 r = {fast_exp2(v.x), fast_exp2(v.y)};
    return r;
}
__device__ __forceinline__ f32x2 rcp2(f32x2 v) {
    f32x2 r = {fast_rcp(v.x), fast_rcp(v.y)};
    return r;
}
__device__ __forceinline__ f32x2 sp2(float v) {
    f32x2 r = {v, v};
    return r;
}

// lgkmcnt-only barrier: ds ops drained, global loads stay in flight.
__device__ __forceinline__ void lgkm_barrier() {
    asm volatile("s_waitcnt lgkmcnt(0)" ::: "memory");
    __builtin_amdgcn_s_barrier();
    asm volatile("" ::: "memory");
}

#define MFMA16 __builtin_amdgcn_mfma_f32_16x16x32_bf16

extern "C" __global__ __launch_bounds__(256, 2)
void lstm_s1p(const float* __restrict__ x,
              const float* __restrict__ W_ih,
              const float* __restrict__ W_hh,
              const float* __restrict__ b_ih,
              const float* __restrict__ b_hh,
              const float* __restrict__ W_fc,
              const float* __restrict__ b_fc,
              float* __restrict__ out) {
    const int tid  = threadIdx.x;
    const int lane = tid & 63;
    const int w    = tid >> 6;          // wave id 0..3
    const int n    = lane & 15;         // batch-within-block == B/D column
    const int q    = lane >> 4;         // k-quad / D row group
    const int bid  = blockIdx.x;
    const int batch = bid * 16 + n;

    // double-buffered h plane (hi only): [buf][batch][unit+pad]
    __shared__ __align__(16) unsigned short lds_h[2][16][kStride];

    // ---- A frags: chunk c, A row m -> W row R(m) = 32*(m&3)+8w+2*(m>>2)+c.
    // HW: A row = lane&15 (=n), k = 8q+j; D col = lane&15, row = 4q+reg.
    // => acc_c[r] = gate r of unit u = 8w + 2q + c (ADJACENT units per lane).
    Frag Ah[2];
#pragma unroll
    for (int c = 0; c < 2; ++c) {
        const int   g = n & 3;
        const float s = (g == 2) ? -2.0f * kL2E : -kL2E;
        const int   R = 32 * g + 8 * w + 2 * (n >> 2) + c;
#pragma unroll
        for (int j = 0; j < 8; ++j) {
            Ah[c].u[j] = bf_rne(W_hh[R * 32 + 8 * q + j] * s);
        }
    }

    // ---- x-path constants: units (u0, u0+1) x 4 gates, f32x2-paired ----
    const int u0 = 8 * w + 2 * q;
    f32x2 xwp[4][3], xbp[4];
#pragma unroll
    for (int g = 0; g < 4; ++g) {
        const float s  = (g == 2) ? -2.0f * kL2E : -kL2E;
        const int   R0 = 32 * g + u0, R1 = R0 + 1;
#pragma unroll
        for (int k = 0; k < 3; ++k) {
            f32x2 wv = {W_ih[R0 * 3 + k] * s, W_ih[R1 * 3 + k] * s};
            xwp[g][k] = wv;
        }
        f32x2 bb = {(b_ih[R0] + b_hh[R0]) * s, (b_ih[R1] + b_hh[R1]) * s};
        xbp[g] = bb;
    }

    const float* xb = x + (size_t)batch * kT * 3;

    f32x2 cst = {0.f, 0.f};
    Frag Bh;
#pragma unroll
    for (int j = 0; j < 4; ++j) Bh.d[j] = 0;

    // prologue: xpC = XP(0); xc = x(1)
    f32x4 xpC0, xpC1;
    {
        const float a0 = xb[0], a1 = xb[1], a2 = xb[2];
#pragma unroll
        for (int g = 0; g < 4; ++g) {
            f32x2 p = fma2(sp2(a0), xwp[g][0],
                      fma2(sp2(a1), xwp[g][1],
                      fma2(sp2(a2), xwp[g][2], xbp[g])));
            xpC0[g] = p.x;
            xpC1[g] = p.y;
        }
    }
    float xc0 = xb[3], xc1 = xb[4], xc2 = xb[5];

    // ---- block anti-phase stagger (one-time, ~half step) ----
    if ((bid ^ (bid >> 8)) & 1) {
        __builtin_amdgcn_s_sleep(8);
    }

    for (int t = 0; t < kT; ++t) {
        // ---- 2 MFMA single-pass, C carries exact fp32 xp ----
        // (t=0: Bh=0 -> acc = xp exactly)
        f32x4 a0 = MFMA16(Ah[0].v, Bh.v, xpC0, 0, 0, 0);
        f32x4 a1 = MFMA16(Ah[1].v, Bh.v, xpC1, 0, 0, 0);

        // ---- gate math, f32x2 over (u0, u0+1): acc_c[r] = gate r ----
        const f32x2 one = {1.f, 1.f};
        f32x2 P0 = {a0[0], a1[0]};
        f32x2 P1 = {a0[1], a1[1]};
        f32x2 P2 = {a0[2], a1[2]};
        f32x2 P3 = {a0[3], a1[3]};
        f32x2 Ei = exp22(P0);
        f32x2 Ef = exp22(P1);
        f32x2 Eg = exp22(P2);
        f32x2 Eo = exp22(P3);
        f32x2 pf  = one + Ef;
        f32x2 pi  = one + Ei;
        f32x2 pg  = one + Eg;
        f32x2 tig = pi * pg;
        f32x2 den = tig * pf;
        f32x2 num = fma2(cst, tig, (one - Eg) * pf);
        f32x2 c   = num * rcp2(den);
        cst = c;
        f32x2 ca  = c * sp2(-2.0f * kL2E);
        f32x2 Ec  = exp22(ca);
        Ec.x = fminf(Ec.x, 1e30f);
        Ec.y = fminf(Ec.y, 1e30f);
        f32x2 od  = (one + Eo) * (one + Ec);
        f32x2 h2  = (one - Ec) * rcp2(od);

        // ---- pack: RNE bf16 pair via one cvt_pk, one ds_write_b32 ----
        const unsigned hh = cvt_pk_bf16(h2.x, h2.y);
        const int buf = t & 1;
        *(unsigned*)&lds_h[buf][n][u0] = hh;   // u0 even -> 4B aligned

        lgkm_barrier();

        // ---- post-barrier shadow: B-read, then xp(t+1) + x(t+2) prefetch
        // (their VALU covers the ds_read latency into next loop-top MFMA)
        Bh.q4 = *(const u32x4*)&lds_h[buf][n][8 * q];

        const int tn = (t + 2 < kT) ? t + 2 : kT - 1;
        const float xn0 = xb[tn * 3 + 0];
        const float xn1 = xb[tn * 3 + 1];
        const float xn2 = xb[tn * 3 + 2];
#pragma unroll
        for (int g = 0; g < 4; ++g) {
            f32x2 p = fma2(sp2(xc0), xwp[g][0],
                      fma2(sp2(xc1), xwp[g][1],
                      fma2(sp2(xc2), xwp[g][2], xbp[g])));
            xpC0[g] = p.x;
            xpC1[g] = p.y;
        }
        xc0 = xn0; xc1 = xn1; xc2 = xn2;
    }

    // ---- epilogue (wave 0): h(511) is in lds buf 1 ----
    if (w == 0) {
        Frag Hh;
        Hh.q4 = *(const u32x4*)&lds_h[1][n][8 * q];
        float s0 = 0.f, s1 = 0.f;
#pragma unroll
        for (int j = 0; j < 8; ++j) {
            const float hv = bf_tof(Hh.u[j]);
            const int   u  = 8 * q + j;
            s0 = fmaf(hv, W_fc[u], s0);
            s1 = fmaf(hv, W_fc[32 + u], s1);
        }
        s0 += __shfl_xor(s0, 16, 64); s1 += __shfl_xor(s1, 16, 64);
        s0 += __shfl_xor(s0, 32, 64); s1 += __shfl_xor(s1, 32, 64);
        if (lane < 16) {
            out[(size_t)batch * 2 + 0] = s0 + b_fc[0];
            out[(size_t)batch * 2 + 1] = s1 + b_fc[1];
        }
    }
}

extern "C" void kernel_launch(void* const* d_in, const int* in_sizes, int n_in,
                              void* d_out, int out_size, void* d_ws, size_t ws_size,
                              hipStream_t stream) {
    const float* x    = (const float*)d_in[0];
    const float* W_ih = (const float*)d_in[1];
    const float* W_hh = (const float*)d_in[2];
    const float* b_ih = (const float*)d_in[3];
    const float* b_hh = (const float*)d_in[4];
    const float* W_fc = (const float*)d_in[5];
    const float* b_fc = (const float*)d_in[6];
    float* out = (float*)d_out;

    const int batch = in_sizes[0] / (kT * 3);   // 8192
    dim3 grid(batch / 16);                      // 512 blocks of 4 waves
    dim3 block(256);                            // -> 2 blocks/CU, 2 waves/SIMD
    hipLaunchKernelGGL(lstm_s1p, grid, block, 0, stream,
                       x, W_ih, W_hh, b_ih, b_hh, W_fc, b_fc, out);
}

// Round 13
// 260.700 us; speedup vs baseline: 1.0917x; 1.0917x over previous
//
#include <hip/hip_runtime.h>
#include <math.h>

// LSTM B=8192,T=512,IN=3,H=32,OUT=2 fp32.
// R21 = R19 byte-identical schedule, minus W-lo (single-pass MFMA).
// R20 post-mortem: both cuts delivered their predicted cycles (VALU -38,
// MFMA -70) but the post-barrier reorder ADDED +190 idle: packing
// write->barrier tightly makes all 4 waves arrive in lockstep, then all
// stall together on ds_read->MFMA. R19's ordering (shadow BETWEEN MFMA and
// gates) spreads arrivals and covers latency -- keep it exactly.
// R20 also proved W-lo drop is numerically free (absmax 1.95e-3 unchanged
// vs R19). So R21 = R19 with Al deleted, nothing else moved:
//   MFMA(2, single-pass, C=xp) | shadow: x(t+2) prefetch + xp(t+1) |
//   gates (pk f32x2, fused triple-rcp) | cvt_pk pack | ds_write |
//   lgkm-barrier | ds_read B frag.
// Chassis (R13/R19, measured optimum): 4-wave blocks, 16 batches,
// adjacent-unit A-perm R(m)=32*(m&3)+8w+2*(m>>2)+c (lane units u0=8w+2q,
// u0+1; acc_c[r] = gate r, zero selects), hi-only double-buffered LDS
// [2][16][40] u16, 1 lgkm-only barrier/step, block-parity s_sleep stagger,
// grid 512 x 256 thr = 2 independent blocks/CU = 2 waves/SIMD.

namespace {
constexpr int   kT      = 512;
constexpr float kL2E    = 1.44269504088896340736f;
constexpr int   kStride = 40;   // ushorts per LDS row: 32 units + 8 pad
}

typedef __bf16 bf16x8 __attribute__((ext_vector_type(8)));
typedef float  f32x4  __attribute__((ext_vector_type(4)));
typedef float  f32x2  __attribute__((ext_vector_type(2)));
typedef unsigned int u32x4 __attribute__((ext_vector_type(4)));

union Frag {
    bf16x8 v;
    unsigned short u[8];
    unsigned int   d[4];
    u32x4          q4;
};

__device__ __forceinline__ unsigned short bf_rne(float f) {
    unsigned u = __float_as_uint(f);
    u += 0x7fffu + ((u >> 16) & 1u);
    return (unsigned short)(u >> 16);
}
__device__ __forceinline__ float bf_tof(unsigned short h) {
    return __uint_as_float((unsigned)h << 16);
}
__device__ __forceinline__ float fast_exp2(float v) { return __builtin_amdgcn_exp2f(v); }
__device__ __forceinline__ float fast_rcp(float v)  { return __builtin_amdgcn_rcpf(v); }

// v_cvt_pk_bf16_f32: dst = [lo16 = bf16_rne(a), hi16 = bf16_rne(b)]
__device__ __forceinline__ unsigned cvt_pk_bf16(float a, float b) {
    unsigned r;
    asm("v_cvt_pk_bf16_f32 %0, %1, %2" : "=v"(r) : "v"(a), "v"(b));
    return r;
}

__device__ __forceinline__ f32x2 fma2(f32x2 a, f32x2 b, f32x2 c) {
    return __builtin_elementwise_fma(a, b, c);
}
__device__ __forceinline__ f32x2 exp22(f32x2 v) {
    f32x2 r = {fast_exp2(v.x), fast_exp2(v.y)};
    return r;
}
__device__ __forceinline__ f32x2 rcp2(f32x2 v) {
    f32x2 r = {fast_rcp(v.x), fast_rcp(v.y)};
    return r;
}
__device__ __forceinline__ f32x2 sp2(float v) {
    f32x2 r = {v, v};
    return r;
}

// lgkmcnt-only barrier: ds ops drained, global loads stay in flight.
__device__ __forceinline__ void lgkm_barrier() {
    asm volatile("s_waitcnt lgkmcnt(0)" ::: "memory");
    __builtin_amdgcn_s_barrier();
    asm volatile("" ::: "memory");
}

#define MFMA16 __builtin_amdgcn_mfma_f32_16x16x32_bf16

extern "C" __global__ __launch_bounds__(256, 2)
void lstm_r21(const float* __restrict__ x,
              const float* __restrict__ W_ih,
              const float* __restrict__ W_hh,
              const float* __restrict__ b_ih,
              const float* __restrict__ b_hh,
              const float* __restrict__ W_fc,
              const float* __restrict__ b_fc,
              float* __restrict__ out) {
    const int tid  = threadIdx.x;
    const int lane = tid & 63;
    const int w    = tid >> 6;          // wave id 0..3
    const int n    = lane & 15;         // batch-within-block == B/D column
    const int q    = lane >> 4;         // k-quad / D row group
    const int bid  = blockIdx.x;
    const int batch = bid * 16 + n;

    // double-buffered h plane (hi only): [buf][batch][unit+pad]
    __shared__ __align__(16) unsigned short lds_h[2][16][kStride];

    // ---- A frags: chunk c, A row m -> W row R(m) = 32*(m&3)+8w+2*(m>>2)+c.
    // HW: A row = lane&15 (=n), k = 8q+j; D col = lane&15, row = 4q+reg.
    // => acc_c[r] = gate r of unit u = 8w + 2q + c (ADJACENT units per lane).
    Frag Ah[2];
#pragma unroll
    for (int c = 0; c < 2; ++c) {
        const int   g = n & 3;
        const float s = (g == 2) ? -2.0f * kL2E : -kL2E;
        const int   R = 32 * g + 8 * w + 2 * (n >> 2) + c;
#pragma unroll
        for (int j = 0; j < 8; ++j) {
            Ah[c].u[j] = bf_rne(W_hh[R * 32 + 8 * q + j] * s);
        }
    }

    // ---- x-path constants: units (u0, u0+1) x 4 gates, f32x2-paired ----
    const int u0 = 8 * w + 2 * q;
    f32x2 xwp[4][3], xbp[4];
#pragma unroll
    for (int g = 0; g < 4; ++g) {
        const float s  = (g == 2) ? -2.0f * kL2E : -kL2E;
        const int   R0 = 32 * g + u0, R1 = R0 + 1;
#pragma unroll
        for (int k = 0; k < 3; ++k) {
            f32x2 wv = {W_ih[R0 * 3 + k] * s, W_ih[R1 * 3 + k] * s};
            xwp[g][k] = wv;
        }
        f32x2 bb = {(b_ih[R0] + b_hh[R0]) * s, (b_ih[R1] + b_hh[R1]) * s};
        xbp[g] = bb;
    }

    const float* xb = x + (size_t)batch * kT * 3;

    f32x2 cst = {0.f, 0.f};
    Frag Bh;
#pragma unroll
    for (int j = 0; j < 4; ++j) Bh.d[j] = 0;

    // prologue: xpC = XP(0); xc = x(1)
    f32x4 xpC0, xpC1;
    {
        const float a0 = xb[0], a1 = xb[1], a2 = xb[2];
#pragma unroll
        for (int g = 0; g < 4; ++g) {
            f32x2 p = fma2(sp2(a0), xwp[g][0],
                      fma2(sp2(a1), xwp[g][1],
                      fma2(sp2(a2), xwp[g][2], xbp[g])));
            xpC0[g] = p.x;
            xpC1[g] = p.y;
        }
    }
    float xc0 = xb[3], xc1 = xb[4], xc2 = xb[5];

    // ---- block anti-phase stagger (one-time, ~half step) ----
    if ((bid ^ (bid >> 8)) & 1) {
        __builtin_amdgcn_s_sleep(8);
    }

    for (int t = 0; t < kT; ++t) {
        // ---- 2 MFMA single-pass, C carries exact fp32 xp ----
        // (t=0: Bh=0 -> acc = xp exactly)
        f32x4 a0 = MFMA16(Ah[0].v, Bh.v, xpC0, 0, 0, 0);
        f32x4 a1 = MFMA16(Ah[1].v, Bh.v, xpC1, 0, 0, 0);

        // ---- shadow work (R19 position: between MFMA and gates):
        // prefetch x(t+2), XP(t+1) from held x(t+1) — covers MFMA latency
        // and spreads barrier arrivals across waves.
        const int tn = (t + 2 < kT) ? t + 2 : kT - 1;
        const float xn0 = xb[tn * 3 + 0];
        const float xn1 = xb[tn * 3 + 1];
        const float xn2 = xb[tn * 3 + 2];
#pragma unroll
        for (int g = 0; g < 4; ++g) {
            f32x2 p = fma2(sp2(xc0), xwp[g][0],
                      fma2(sp2(xc1), xwp[g][1],
                      fma2(sp2(xc2), xwp[g][2], xbp[g])));
            xpC0[g] = p.x;
            xpC1[g] = p.y;
        }

        // ---- gate math, f32x2 over (u0, u0+1): acc_c[r] = gate r ----
        const f32x2 one = {1.f, 1.f};
        f32x2 P0 = {a0[0], a1[0]};
        f32x2 P1 = {a0[1], a1[1]};
        f32x2 P2 = {a0[2], a1[2]};
        f32x2 P3 = {a0[3], a1[3]};
        f32x2 Ei = exp22(P0);
        f32x2 Ef = exp22(P1);
        f32x2 Eg = exp22(P2);
        f32x2 Eo = exp22(P3);
        f32x2 pf  = one + Ef;
        f32x2 pi  = one + Ei;
        f32x2 pg  = one + Eg;
        f32x2 tig = pi * pg;
        f32x2 den = tig * pf;
        f32x2 num = fma2(cst, tig, (one - Eg) * pf);
        f32x2 c   = num * rcp2(den);
        cst = c;
        f32x2 ca  = c * sp2(-2.0f * kL2E);
        f32x2 Ec  = exp22(ca);
        Ec.x = fminf(Ec.x, 1e30f);
        Ec.y = fminf(Ec.y, 1e30f);
        f32x2 od  = (one + Eo) * (one + Ec);
        f32x2 h2  = (one - Ec) * rcp2(od);

        // ---- pack: RNE bf16 pair via one cvt_pk, one ds_write_b32 ----
        const unsigned hh = cvt_pk_bf16(h2.x, h2.y);
        const int buf = t & 1;
        *(unsigned*)&lds_h[buf][n][u0] = hh;   // u0 even -> 4B aligned

        lgkm_barrier();

        // ---- B frag for next step: units 8q..8q+7 of batch n ----
        Bh.q4 = *(const u32x4*)&lds_h[buf][n][8 * q];

        xc0 = xn0; xc1 = xn1; xc2 = xn2;
    }

    // ---- epilogue (wave 0): h(511) is in lds buf 1 ----
    if (w == 0) {
        Frag Hh;
        Hh.q4 = *(const u32x4*)&lds_h[1][n][8 * q];
        float s0 = 0.f, s1 = 0.f;
#pragma unroll
        for (int j = 0; j < 8; ++j) {
            const float hv = bf_tof(Hh.u[j]);
            const int   u  = 8 * q + j;
            s0 = fmaf(hv, W_fc[u], s0);
            s1 = fmaf(hv, W_fc[32 + u], s1);
        }
        s0 += __shfl_xor(s0, 16, 64); s1 += __shfl_xor(s1, 16, 64);
        s0 += __shfl_xor(s0, 32, 64); s1 += __shfl_xor(s1, 32, 64);
        if (lane < 16) {
            out[(size_t)batch * 2 + 0] = s0 + b_fc[0];
            out[(size_t)batch * 2 + 1] = s1 + b_fc[1];
        }
    }
}

extern "C" void kernel_launch(void* const* d_in, const int* in_sizes, int n_in,
                              void* d_out, int out_size, void* d_ws, size_t ws_size,
                              hipStream_t stream) {
    const float* x    = (const float*)d_in[0];
    const float* W_ih = (const float*)d_in[1];
    const float* W_hh = (const float*)d_in[2];
    const float* b_ih = (const float*)d_in[3];
    const float* b_hh = (const float*)d_in[4];
    const float* W_fc = (const float*)d_in[5];
    const float* b_fc = (const float*)d_in[6];
    float* out = (float*)d_out;

    const int batch = in_sizes[0] / (kT * 3);   // 8192
    dim3 grid(batch / 16);                      // 512 blocks of 4 waves
    dim3 block(256);                            // -> 2 blocks/CU, 2 waves/SIMD
    hipLaunchKernelGGL(lstm_r21, grid, block, 0, stream,
                       x, W_ih, W_hh, b_ih, b_hh, W_fc, b_fc, out);
}

// Round 14
// 233.529 us; speedup vs baseline: 1.2188x; 1.1164x over previous
//
#include <hip/hip_runtime.h>
#include <math.h>

// LSTM B=8192,T=512,IN=3,H=32,OUT=2 fp32.
// R22 = R21 + priority choreography + unroll-2 ping-pong.
// R21 (best, ~205us rocprof): trans-issue-dominated. Per SIMD-step ~940cyc:
// VALU 550 (28 trans x 16cyc pipe occupancy + ~100 other = the algebraic
// floor: 5 exp2 + 2 rcp per unit, no packed trans on CDNA), MFMA 65,
// idle ~325. Remaining lever is idle only.
// Riders:
// 1) s_setprio: prio=1 on the critical path (MFMA -> gates -> write ->
//    barrier -> ds_read), prio=0 during the slack shadow (x prefetch + xp
//    recompute). With the two co-resident waves (different blocks,
//    staggered) one is in slack while the other is on its chain -> the
//    chain wave wins issue arbitration (T5 role-diversity condition that
//    R21's symmetric schedule lacked).
// 2) Unroll-2: static buf per copy + ping-pong x-register sets (removes
//    3 reg copies + buf arith per step).
// Everything else byte-identical to R21 (order empirically tuned: R20's
// reorder cost +190 idle): single-pass MFMA acc=Ah*Bh+xp, adjacent-unit
// A-perm R(m)=32*(m&3)+8w+2*(m>>2)+c, pk-f32x2 gates w/ fused triple-rcp,
// cvt_pk pack, hi-only dbuf LDS [2][16][40], lgkm-only barrier (1/step),
// block-parity s_sleep stagger, grid 512 x 256 thr = 2 blocks/CU.

namespace {
constexpr int   kT      = 512;
constexpr float kL2E    = 1.44269504088896340736f;
constexpr int   kStride = 40;   // ushorts per LDS row: 32 units + 8 pad
}

typedef __bf16 bf16x8 __attribute__((ext_vector_type(8)));
typedef float  f32x4  __attribute__((ext_vector_type(4)));
typedef float  f32x2  __attribute__((ext_vector_type(2)));
typedef unsigned int u32x4 __attribute__((ext_vector_type(4)));

union Frag {
    bf16x8 v;
    unsigned short u[8];
    unsigned int   d[4];
    u32x4          q4;
};

__device__ __forceinline__ unsigned short bf_rne(float f) {
    unsigned u = __float_as_uint(f);
    u += 0x7fffu + ((u >> 16) & 1u);
    return (unsigned short)(u >> 16);
}
__device__ __forceinline__ float bf_tof(unsigned short h) {
    return __uint_as_float((unsigned)h << 16);
}
__device__ __forceinline__ float fast_exp2(float v) { return __builtin_amdgcn_exp2f(v); }
__device__ __forceinline__ float fast_rcp(float v)  { return __builtin_amdgcn_rcpf(v); }

// v_cvt_pk_bf16_f32: dst = [lo16 = bf16_rne(a), hi16 = bf16_rne(b)]
__device__ __forceinline__ unsigned cvt_pk_bf16(float a, float b) {
    unsigned r;
    asm("v_cvt_pk_bf16_f32 %0, %1, %2" : "=v"(r) : "v"(a), "v"(b));
    return r;
}

__device__ __forceinline__ f32x2 fma2(f32x2 a, f32x2 b, f32x2 c) {
    return __builtin_elementwise_fma(a, b, c);
}
__device__ __forceinline__ f32x2 exp22(f32x2 v) {
    f32x2 r = {fast_exp2(v.x), fast_exp2(v.y)};
    return r;
}
__device__ __forceinline__ f32x2 rcp2(f32x2 v) {
    f32x2 r = {fast_rcp(v.x), fast_rcp(v.y)};
    return r;
}
__device__ __forceinline__ f32x2 sp2(float v) {
    f32x2 r = {v, v};
    return r;
}

// lgkmcnt-only barrier: ds ops drained, global loads stay in flight.
__device__ __forceinline__ void lgkm_barrier() {
    asm volatile("s_waitcnt lgkmcnt(0)" ::: "memory");
    __builtin_amdgcn_s_barrier();
    asm volatile("" ::: "memory");
}

#define MFMA16 __builtin_amdgcn_mfma_f32_16x16x32_bf16

extern "C" __global__ __launch_bounds__(256, 2)
void lstm_r22(const float* __restrict__ x,
              const float* __restrict__ W_ih,
              const float* __restrict__ W_hh,
              const float* __restrict__ b_ih,
              const float* __restrict__ b_hh,
              const float* __restrict__ W_fc,
              const float* __restrict__ b_fc,
              float* __restrict__ out) {
    const int tid  = threadIdx.x;
    const int lane = tid & 63;
    const int w    = tid >> 6;          // wave id 0..3
    const int n    = lane & 15;         // batch-within-block == B/D column
    const int q    = lane >> 4;         // k-quad / D row group
    const int bid  = blockIdx.x;
    const int batch = bid * 16 + n;

    // double-buffered h plane (hi only): [buf][batch][unit+pad]
    __shared__ __align__(16) unsigned short lds_h[2][16][kStride];

    // ---- A frags: chunk c, A row m -> W row R(m) = 32*(m&3)+8w+2*(m>>2)+c.
    // => acc_c[r] = gate r of unit u = 8w + 2q + c (adjacent units per lane).
    Frag Ah[2];
#pragma unroll
    for (int c = 0; c < 2; ++c) {
        const int   g = n & 3;
        const float s = (g == 2) ? -2.0f * kL2E : -kL2E;
        const int   R = 32 * g + 8 * w + 2 * (n >> 2) + c;
#pragma unroll
        for (int j = 0; j < 8; ++j) {
            Ah[c].u[j] = bf_rne(W_hh[R * 32 + 8 * q + j] * s);
        }
    }

    // ---- x-path constants: units (u0, u0+1) x 4 gates, f32x2-paired ----
    const int u0 = 8 * w + 2 * q;
    f32x2 xwp[4][3], xbp[4];
#pragma unroll
    for (int g = 0; g < 4; ++g) {
        const float s  = (g == 2) ? -2.0f * kL2E : -kL2E;
        const int   R0 = 32 * g + u0, R1 = R0 + 1;
#pragma unroll
        for (int k = 0; k < 3; ++k) {
            f32x2 wv = {W_ih[R0 * 3 + k] * s, W_ih[R1 * 3 + k] * s};
            xwp[g][k] = wv;
        }
        f32x2 bb = {(b_ih[R0] + b_hh[R0]) * s, (b_ih[R1] + b_hh[R1]) * s};
        xbp[g] = bb;
    }

    const float* xb = x + (size_t)batch * kT * 3;

    f32x2 cst = {0.f, 0.f};
    Frag Bh;
#pragma unroll
    for (int j = 0; j < 4; ++j) Bh.d[j] = 0;

    // prologue: xpC = XP(0); xcA = x(1)
    f32x4 xpC0, xpC1;
    {
        const float a0 = xb[0], a1 = xb[1], a2 = xb[2];
#pragma unroll
        for (int g = 0; g < 4; ++g) {
            f32x2 p = fma2(sp2(a0), xwp[g][0],
                      fma2(sp2(a1), xwp[g][1],
                      fma2(sp2(a2), xwp[g][2], xbp[g])));
            xpC0[g] = p.x;
            xpC1[g] = p.y;
        }
    }
    float xcA0 = xb[3], xcA1 = xb[4], xcA2 = xb[5];  // x(t+1), even steps
    float xcB0 = 0.f,   xcB1 = 0.f,   xcB2 = 0.f;    // x(t+1), odd steps

    // ---- block anti-phase stagger (one-time, ~half step) ----
    if ((bid ^ (bid >> 8)) & 1) {
        __builtin_amdgcn_s_sleep(8);
    }

    __builtin_amdgcn_s_setprio(1);

    // step body: consumes held x(t+1) regs (hx), loads x(t+2) into (lx).
#define STEP(T, BUF, hx0, hx1, hx2, lx0, lx1, lx2)                          \
    {                                                                        \
        /* 2 MFMA single-pass, C carries exact fp32 xp (t=0: Bh=0) */        \
        f32x4 a0 = MFMA16(Ah[0].v, Bh.v, xpC0, 0, 0, 0);                     \
        f32x4 a1 = MFMA16(Ah[1].v, Bh.v, xpC1, 0, 0, 0);                     \
        /* slack shadow: yield issue to the partner wave's critical path */  \
        __builtin_amdgcn_s_setprio(0);                                       \
        const int tn = ((T) + 2 < kT) ? (T) + 2 : kT - 1;                    \
        lx0 = xb[tn * 3 + 0];                                                \
        lx1 = xb[tn * 3 + 1];                                                \
        lx2 = xb[tn * 3 + 2];                                                \
        _Pragma("unroll")                                                    \
        for (int g = 0; g < 4; ++g) {                                        \
            f32x2 p = fma2(sp2(hx0), xwp[g][0],                              \
                      fma2(sp2(hx1), xwp[g][1],                              \
                      fma2(sp2(hx2), xwp[g][2], xbp[g])));                   \
            xpC0[g] = p.x;                                                   \
            xpC1[g] = p.y;                                                   \
        }                                                                    \
        __builtin_amdgcn_s_setprio(1);                                       \
        /* gates, f32x2 over (u0, u0+1): acc_c[r] = gate r */                \
        const f32x2 one = {1.f, 1.f};                                        \
        f32x2 P0 = {a0[0], a1[0]};                                           \
        f32x2 P1 = {a0[1], a1[1]};                                           \
        f32x2 P2 = {a0[2], a1[2]};                                           \
        f32x2 P3 = {a0[3], a1[3]};                                           \
        f32x2 Ei = exp22(P0);                                                \
        f32x2 Ef = exp22(P1);                                                \
        f32x2 Eg = exp22(P2);                                                \
        f32x2 Eo = exp22(P3);                                                \
        f32x2 pf  = one + Ef;                                                \
        f32x2 pi  = one + Ei;                                                \
        f32x2 pg  = one + Eg;                                                \
        f32x2 tig = pi * pg;                                                 \
        f32x2 den = tig * pf;                                                \
        f32x2 num = fma2(cst, tig, (one - Eg) * pf);                         \
        f32x2 c   = num * rcp2(den);                                         \
        cst = c;                                                             \
        f32x2 ca  = c * sp2(-2.0f * kL2E);                                   \
        f32x2 Ec  = exp22(ca);                                               \
        Ec.x = fminf(Ec.x, 1e30f);                                           \
        Ec.y = fminf(Ec.y, 1e30f);                                           \
        f32x2 od  = (one + Eo) * (one + Ec);                                 \
        f32x2 h2  = (one - Ec) * rcp2(od);                                   \
        /* pack + exchange */                                                \
        const unsigned hh = cvt_pk_bf16(h2.x, h2.y);                         \
        *(unsigned*)&lds_h[BUF][n][u0] = hh;                                 \
        lgkm_barrier();                                                      \
        Bh.q4 = *(const u32x4*)&lds_h[BUF][n][8 * q];                        \
    }

    for (int t = 0; t < kT; t += 2) {
        STEP(t,     0, xcA0, xcA1, xcA2, xcB0, xcB1, xcB2)
        STEP(t + 1, 1, xcB0, xcB1, xcB2, xcA0, xcA1, xcA2)
    }
#undef STEP

    // ---- epilogue (wave 0): h(511) is in lds buf 1 ----
    if (w == 0) {
        Frag Hh;
        Hh.q4 = *(const u32x4*)&lds_h[1][n][8 * q];
        float s0 = 0.f, s1 = 0.f;
#pragma unroll
        for (int j = 0; j < 8; ++j) {
            const float hv = bf_tof(Hh.u[j]);
            const int   u  = 8 * q + j;
            s0 = fmaf(hv, W_fc[u], s0);
            s1 = fmaf(hv, W_fc[32 + u], s1);
        }
        s0 += __shfl_xor(s0, 16, 64); s1 += __shfl_xor(s1, 16, 64);
        s0 += __shfl_xor(s0, 32, 64); s1 += __shfl_xor(s1, 32, 64);
        if (lane < 16) {
            out[(size_t)batch * 2 + 0] = s0 + b_fc[0];
            out[(size_t)batch * 2 + 1] = s1 + b_fc[1];
        }
    }
}

extern "C" void kernel_launch(void* const* d_in, const int* in_sizes, int n_in,
                              void* d_out, int out_size, void* d_ws, size_t ws_size,
                              hipStream_t stream) {
    const float* x    = (const float*)d_in[0];
    const float* W_ih = (const float*)d_in[1];
    const float* W_hh = (const float*)d_in[2];
    const float* b_ih = (const float*)d_in[3];
    const float* b_hh = (const float*)d_in[4];
    const float* W_fc = (const float*)d_in[5];
    const float* b_fc = (const float*)d_in[6];
    float* out = (float*)d_out;

    const int batch = in_sizes[0] / (kT * 3);   // 8192
    dim3 grid(batch / 16);                      // 512 blocks of 4 waves
    dim3 block(256);                            // -> 2 blocks/CU, 2 waves/SIMD
    hipLaunchKernelGGL(lstm_r22, grid, block, 0, stream,
                       x, W_ih, W_hh, b_ih, b_hh, W_fc, b_fc, out);
}